// Round 11
// baseline (29.245 us; speedup 1.0000x reference)
//
#include <hip/hip_runtime.h>

typedef float f32x2 __attribute__((ext_vector_type(2)));
typedef f32x2 c32;   // [0]=re, [1]=im  -- native VGPR pair, no asm glue movs

__device__ __forceinline__ c32 mkc(float x, float y) { c32 r; r[0] = x; r[1] = y; return r; }

// complex mul/mad via packed fp32 VOP3P (2 instrs instead of 4)
__device__ __forceinline__ c32 cmul(c32 a, c32 b) {
    c32 r;
    asm("v_pk_mul_f32 %0, %1, %2 op_sel:[0,0] op_sel_hi:[0,1]\n\t"
        "v_pk_fma_f32 %0, %1, %2, %0 op_sel:[1,1,0] op_sel_hi:[1,0,1] neg_lo:[1,0,0]"
        : "=&v"(r) : "v"(a), "v"(b));
    return r;
}
__device__ __forceinline__ c32 cmad(c32 a, c32 b, c32 acc) {
    asm("v_pk_fma_f32 %0, %1, %2, %0 op_sel:[0,0,0] op_sel_hi:[0,1,1]\n\t"
        "v_pk_fma_f32 %0, %1, %2, %0 op_sel:[1,1,0] op_sel_hi:[1,0,1] neg_lo:[1,0,0]"
        : "+v"(acc) : "v"(a), "v"(b));
    return acc;
}

// ---------------- gate-matrix build: device func, lanes 0..19 --------------

__device__ __forceinline__ void mk_u3(float th, float ph, float la, c32 U[2][2]) {
    float ct = cosf(0.5f * th), st = sinf(0.5f * th);
    U[0][0] = mkc(ct, 0.f);
    U[0][1] = mkc(-cosf(la) * st, -sinf(la) * st);
    U[1][0] = mkc(cosf(ph) * st, sinf(ph) * st);
    U[1][1] = mkc(cosf(ph + la) * ct, sinf(ph + la) * ct);
}

__device__ __forceinline__ void lmul_kron(const c32 A[2][2], const c32 B[2][2], c32 m[4]) {
    c32 t[4];
#pragma unroll
    for (int r = 0; r < 4; ++r) {
        c32 acc = mkc(0.f, 0.f);
#pragma unroll
        for (int k = 0; k < 4; ++k)
            acc = cmad(cmul(A[r >> 1][k >> 1], B[r & 1][k & 1]), m[k], acc);
        t[r] = acc;
    }
#pragma unroll
    for (int r = 0; r < 4; ++r) m[r] = t[r];
}

// thread t in [0,20): build column (t&3) of gate matrix (t>>2) into gml (LDS)
__device__ void build_col(const float* __restrict__ w, int t, c32* gml) {
    const int g = t >> 2, c = t & 3;
    const float* p = w + g * 15;
    const int c0 = c >> 1, c1 = c & 1;
    c32 A[2][2], B[2][2], m[4], tmp;

    mk_u3(p[0], p[1], p[2], A);
    mk_u3(p[3], p[4], p[5], B);
#pragma unroll
    for (int r = 0; r < 4; ++r) m[r] = cmul(A[r >> 1][c0], B[r & 1][c1]);
    tmp = m[2]; m[2] = m[3]; m[3] = tmp;                 // CNOT(w0->w1)
    {
        float cc = cosf(0.5f * p[6]), s = sinf(0.5f * p[6]);
        A[0][0] = mkc(cc, 0.f); A[0][1] = mkc(-s, 0.f);
        A[1][0] = mkc(s, 0.f);  A[1][1] = mkc(cc, 0.f);
        float cz = cosf(0.5f * p[7]), sz = sinf(0.5f * p[7]);
        B[0][0] = mkc(cz, -sz); B[0][1] = mkc(0.f, 0.f);
        B[1][0] = mkc(0.f, 0.f); B[1][1] = mkc(cz, sz);
        lmul_kron(A, B, m);
    }
    tmp = m[1]; m[1] = m[3]; m[3] = tmp;                 // CNOT(w1->w0)
    {
        float cc = cosf(0.5f * p[8]), s = sinf(0.5f * p[8]);
        A[0][0] = mkc(cc, 0.f); A[0][1] = mkc(-s, 0.f);
        A[1][0] = mkc(s, 0.f);  A[1][1] = mkc(cc, 0.f);
        B[0][0] = mkc(1.f, 0.f); B[0][1] = mkc(0.f, 0.f);
        B[1][0] = mkc(0.f, 0.f); B[1][1] = mkc(1.f, 0.f);
        lmul_kron(A, B, m);
    }
    tmp = m[2]; m[2] = m[3]; m[3] = tmp;                 // CNOT(w0->w1)
    mk_u3(p[9], p[10], p[11], A);
    mk_u3(p[12], p[13], p[14], B);
    lmul_kron(A, B, m);
#pragma unroll
    for (int r = 0; r < 4; ++r) gml[g * 16 + r * 4 + c] = m[r];
}

// ---------------- register-window simulator: 4 states per wave ------------
// qubit q <-> bit (7-q).  Lane holds 16 amps (4 window qubits in-register).

#define STRIDE 260   // c32 per state slice: 256 used + 4 stagger

__device__ __forceinline__ int swz8(int i) { return i ^ (i >> 4); }
__host__ __device__ constexpr int cswz8(int i) { return i ^ (i >> 4); }

template<int P3, int P2, int P1, int P0>
struct BitMap {
    __device__ static int scatterDyn(int v) {
        return (((v >> 3) & 1) << P3) | (((v >> 2) & 1) << P2) |
               (((v >> 1) & 1) << P1) | ((v & 1) << P0);
    }
    static constexpr int scatter(int v) {
        return (((v >> 3) & 1) << P3) | (((v >> 2) & 1) << P2) |
               (((v >> 1) & 1) << P1) | ((v & 1) << P0);
    }
};

// window maps (reg bit k -> global bit) and lane maps (complement)
using WA = BitMap<7, 6, 5, 4>;  using LA = BitMap<3, 2, 1, 0>;   // q0,q1,q2,q3
using WB = BitMap<3, 2, 1, 0>;  using LB = BitMap<7, 6, 5, 4>;   // q4,q5,q6,q7
using WC = BitMap<7, 4, 3, 0>;  using LC = BitMap<6, 5, 2, 1>;   // q0,q3,q4,q7
using WD = BitMap<7, 5, 3, 1>;  using LD = BitMap<6, 4, 2, 0>;   // q0,q2,q4,q6

// re-layout: write with old map, read with new map (wave-private LDS slice)
template<class WO, class LO, class WN, class LN>
__device__ __forceinline__ void transition(c32* sl, int c, c32 s[16]) {
    const int uo = swz8(LO::scatterDyn(c));
#pragma unroll
    for (int r = 0; r < 16; ++r) sl[uo ^ cswz8(WO::scatter(r))] = s[r];
    const int un = swz8(LN::scatterDyn(c));
#pragma unroll
    for (int r = 0; r < 16; ++r) s[r] = sl[un ^ cswz8(WN::scatter(r))];
}

constexpr int freePos(int A, int B, int k) {
    int cnt = 0;
    for (int p = 0; p < 4; ++p)
        if (p != A && p != B) { if (cnt == k) return p; ++cnt; }
    return -1;
}

// apply 4x4 gate; w0 at reg-bit A, w1 at reg-bit B (row = 2*bitA + bitB)
template<int A, int B>
__device__ __forceinline__ void gate(const c32 m[16], c32 s[16]) {
    constexpr int C0 = freePos(A, B, 0);
    constexpr int C1 = freePos(A, B, 1);
#pragma unroll
    for (int q = 0; q < 4; ++q) {
        const int base = ((q & 1) << C0) | (((q >> 1) & 1) << C1);
        const int i00 = base, i01 = base | (1 << B), i10 = base | (1 << A),
                  i11 = base | (1 << A) | (1 << B);
        c32 a0 = s[i00], a1 = s[i01], a2 = s[i10], a3 = s[i11];
        c32 r0 = cmul(m[0],  a0); r0 = cmad(m[1],  a1, r0); r0 = cmad(m[2],  a2, r0); r0 = cmad(m[3],  a3, r0);
        c32 r1 = cmul(m[4],  a0); r1 = cmad(m[5],  a1, r1); r1 = cmad(m[6],  a2, r1); r1 = cmad(m[7],  a3, r1);
        c32 r2 = cmul(m[8],  a0); r2 = cmad(m[9],  a1, r2); r2 = cmad(m[10], a2, r2); r2 = cmad(m[11], a3, r2);
        c32 r3 = cmul(m[12], a0); r3 = cmad(m[13], a1, r3); r3 = cmad(m[14], a2, r3); r3 = cmad(m[15], a3, r3);
        s[i00] = r0; s[i01] = r1; s[i10] = r2; s[i11] = r3;
    }
}

__device__ __forceinline__ void loadm(const c32* gml, int idx, c32 m[16]) {
#pragma unroll
    for (int k = 0; k < 16; ++k) m[k] = gml[idx * 16 + k];   // LDS broadcast
}

__global__ __launch_bounds__(64, 4) void sim_kernel(const float* __restrict__ x,
                                                    const float* __restrict__ w,
                                                    float* __restrict__ out) {
    __shared__ c32 TR[4 * STRIDE];
    __shared__ c32 GML[80];
    const int lane = threadIdx.x;      // one wave per block
    const int st   = lane >> 4;        // state within wave (0..3)
    const int c    = lane & 15;        // 16 lanes per state
    const int b    = blockIdx.x * 4 + st;

    // issue x loads first; matrix build overlaps the load latency
    const float* xb = x + (size_t)b * 256 + c;
    float v[16];
#pragma unroll
    for (int r = 0; r < 16; ++r) v[r] = xb[r << 4];

    if (lane < 20) build_col(w, lane, GML);
    // single wave: exec-mask divergence reconverges; lgkmcnt orders GML use.

    float ss = 0.f;
#pragma unroll
    for (int r = 0; r < 16; ++r) ss = fmaf(v[r], v[r], ss);
#pragma unroll
    for (int o = 8; o; o >>= 1) ss += __shfl_xor(ss, o, 64);
    const float inv = 1.0f / sqrtf(ss);
    c32 s[16];
#pragma unroll
    for (int r = 0; r < 16; ++r) s[r] = mkc(v[r] * inv, 0.f);

    c32* sl = TR + st * STRIDE;
    c32 m[16];

    // ---- LAYER1 x2 (rolled) ----------------------------------------------
#pragma unroll 1
    for (int pass = 0; pass < 2; ++pass) {
        loadm(GML, pass, m);
        gate<3, 2>(m, s); gate<1, 0>(m, s); gate<2, 1>(m, s);   // (0,1)(2,3)(1,2)
        transition<WA, LA, WB, LB>(sl, c, s);
        gate<3, 2>(m, s); gate<1, 0>(m, s); gate<2, 1>(m, s);   // (4,5)(6,7)(5,6)
        transition<WB, LB, WC, LC>(sl, c, s);
        gate<2, 1>(m, s); gate<0, 3>(m, s);                     // (3,4)(7,0)
        if (pass == 0) transition<WC, LC, WA, LA>(sl, c, s);
        else           transition<WC, LC, WD, LD>(sl, c, s);
    }

    // ---- LAYER2 x2 in window D (no transitions) --------------------------
#pragma unroll 1
    for (int pp = 0; pp < 2; ++pp) {
        loadm(GML, 2 + pp, m);
        gate<2, 1>(m, s); gate<0, 3>(m, s);                     // (2,4)(6,0)
        gate<3, 2>(m, s); gate<1, 0>(m, s);                     // (0,2)(4,6)
    }
    // ---- LAYER3 ----------------------------------------------------------
    loadm(GML, 4, m);
    gate<2, 0>(m, s);                                           // (2,6)

    // epilogue in window D: qubit2 = reg-bit 2, qubit6 = reg-bit 0
    float e0 = 0, e1 = 0, e2 = 0, e3 = 0, e4 = 0, e5 = 0, e6 = 0, e7 = 0, e8 = 0;
#pragma unroll
    for (int q = 0; q < 4; ++q) {
        const int f = ((q & 1) << 1) | ((q & 2) << 2);   // free bits r1, r3
        c32 a00 = s[f], a01 = s[f | 1], a10 = s[f | 4], a11 = s[f | 5];
        float n00 = a00[0] * a00[0] + a00[1] * a00[1];
        float n01 = a01[0] * a01[0] + a01[1] * a01[1];
        float n10 = a10[0] * a10[0] + a10[1] * a10[1];
        float n11 = a11[0] * a11[0] + a11[1] * a11[1];
        float z2r = a00[0] * a10[0] + a00[1] * a10[1] + a01[0] * a11[0] + a01[1] * a11[1];
        float z2i = a00[0] * a10[1] - a00[1] * a10[0] + a01[0] * a11[1] - a01[1] * a11[0];
        float z6r = a00[0] * a01[0] + a00[1] * a01[1] + a10[0] * a11[0] + a10[1] * a11[1];
        float z6i = a00[0] * a01[1] - a00[1] * a01[0] + a10[0] * a11[1] - a10[1] * a11[0];
        float w1r = a00[0] * a11[0] + a00[1] * a11[1];   // Re(conj(a00)*a11)
        float w2r = a01[0] * a10[0] + a01[1] * a10[1];   // Re(conj(a01)*a10)
        e0 += 2.f * z2r;  e1 += 2.f * z2i;  e2 += n00 + n01 - n10 - n11;
        e3 += 2.f * z6r;  e4 += 2.f * z6i;  e5 += n00 - n01 + n10 - n11;
        e6 += 2.f * (w1r + w2r);  e7 += 2.f * (w2r - w1r);
        e8 += n00 - n01 - n10 + n11;
    }
    float e[9] = {e0, e1, e2, e3, e4, e5, e6, e7, e8};
#pragma unroll
    for (int mm = 0; mm < 9; ++mm) {
        float vv = e[mm];
#pragma unroll
        for (int o = 8; o; o >>= 1) vv += __shfl_xor(vv, o, 64);
        e[mm] = vv;
    }
    if (c == 0) {
#pragma unroll
        for (int mm = 0; mm < 9; ++mm) out[b * 9 + mm] = e[mm];
    }
}

extern "C" void kernel_launch(void* const* d_in, const int* in_sizes, int n_in,
                              void* d_out, int out_size, void* d_ws, size_t ws_size,
                              hipStream_t stream) {
    const float* x = (const float*)d_in[0];
    const float* w = (const float*)d_in[1];
    float* out = (float*)d_out;

    const int batch = in_sizes[0] / 256;   // 8192
    const int nblocks = batch / 4;         // 4 states per wave, 1 wave per block
    hipLaunchKernelGGL(sim_kernel, dim3(nblocks), dim3(64), 0, stream, x, w, out);
}

// Round 12
// 27.109 us; speedup vs baseline: 1.0788x; 1.0788x over previous
//
#include <hip/hip_runtime.h>

typedef float f32x2 __attribute__((ext_vector_type(2)));
typedef f32x2 c32;   // [0]=re, [1]=im

__device__ __forceinline__ c32 mkc(float x, float y) { c32 r; r[0] = x; r[1] = y; return r; }

// complex mul/mad via packed fp32 VOP3P
__device__ __forceinline__ c32 cmul(c32 a, c32 b) {
    c32 r;
    asm("v_pk_mul_f32 %0, %1, %2 op_sel:[0,0] op_sel_hi:[0,1]\n\t"
        "v_pk_fma_f32 %0, %1, %2, %0 op_sel:[1,1,0] op_sel_hi:[1,0,1] neg_lo:[1,0,0]"
        : "=&v"(r) : "v"(a), "v"(b));
    return r;
}
__device__ __forceinline__ c32 cmad(c32 a, c32 b, c32 acc) {
    asm("v_pk_fma_f32 %0, %1, %2, %0 op_sel:[0,0,0] op_sel_hi:[0,1,1]\n\t"
        "v_pk_fma_f32 %0, %1, %2, %0 op_sel:[1,1,0] op_sel_hi:[1,0,1] neg_lo:[1,0,0]"
        : "+v"(acc) : "v"(a), "v"(b));
    return acc;
}

// ---------------- gate-matrix build: lanes 0..19, fast transcendentals -----

__device__ __forceinline__ void mk_u3(float th, float ph, float la, c32 U[2][2]) {
    float ct = __cosf(0.5f * th), st = __sinf(0.5f * th);
    U[0][0] = mkc(ct, 0.f);
    U[0][1] = mkc(-__cosf(la) * st, -__sinf(la) * st);
    U[1][0] = mkc(__cosf(ph) * st, __sinf(ph) * st);
    U[1][1] = mkc(__cosf(ph + la) * ct, __sinf(ph + la) * ct);
}

__device__ __forceinline__ void lmul_kron(const c32 A[2][2], const c32 B[2][2], c32 m[4]) {
    c32 t[4];
#pragma unroll
    for (int r = 0; r < 4; ++r) {
        c32 acc = mkc(0.f, 0.f);
#pragma unroll
        for (int k = 0; k < 4; ++k)
            acc = cmad(cmul(A[r >> 1][k >> 1], B[r & 1][k >> 0 & 1]), m[k], acc);
        t[r] = acc;
    }
#pragma unroll
    for (int r = 0; r < 4; ++r) m[r] = t[r];
}

// thread t in [0,20): build column (t&3) of gate matrix (t>>2) into gml (LDS)
__device__ void build_col(const float* __restrict__ w, int t, c32* gml) {
    const int g = t >> 2, c = t & 3;
    const float* p = w + g * 15;
    const int c0 = c >> 1, c1 = c & 1;
    c32 A[2][2], B[2][2], m[4], tmp;

    mk_u3(p[0], p[1], p[2], A);
    mk_u3(p[3], p[4], p[5], B);
#pragma unroll
    for (int r = 0; r < 4; ++r) m[r] = cmul(A[r >> 1][c0], B[r & 1][c1]);
    tmp = m[2]; m[2] = m[3]; m[3] = tmp;                 // CNOT(w0->w1)
    {
        float cc = __cosf(0.5f * p[6]), s = __sinf(0.5f * p[6]);
        A[0][0] = mkc(cc, 0.f); A[0][1] = mkc(-s, 0.f);
        A[1][0] = mkc(s, 0.f);  A[1][1] = mkc(cc, 0.f);
        float cz = __cosf(0.5f * p[7]), sz = __sinf(0.5f * p[7]);
        B[0][0] = mkc(cz, -sz); B[0][1] = mkc(0.f, 0.f);
        B[1][0] = mkc(0.f, 0.f); B[1][1] = mkc(cz, sz);
        lmul_kron(A, B, m);
    }
    tmp = m[1]; m[1] = m[3]; m[3] = tmp;                 // CNOT(w1->w0)
    {
        float cc = __cosf(0.5f * p[8]), s = __sinf(0.5f * p[8]);
        A[0][0] = mkc(cc, 0.f); A[0][1] = mkc(-s, 0.f);
        A[1][0] = mkc(s, 0.f);  A[1][1] = mkc(cc, 0.f);
        B[0][0] = mkc(1.f, 0.f); B[0][1] = mkc(0.f, 0.f);
        B[1][0] = mkc(0.f, 0.f); B[1][1] = mkc(1.f, 0.f);
        lmul_kron(A, B, m);
    }
    tmp = m[2]; m[2] = m[3]; m[3] = tmp;                 // CNOT(w0->w1)
    mk_u3(p[9], p[10], p[11], A);
    mk_u3(p[12], p[13], p[14], B);
    lmul_kron(A, B, m);
#pragma unroll
    for (int r = 0; r < 4; ++r) gml[g * 16 + r * 4 + c] = m[r];
}

// ---------------- simulator: 2 states per lane, 8 states per wave ---------
// qubit q <-> bit (7-q).  Lane holds 2x16 amps (4 window qubits in-register).

#define STRIDE 260

__device__ __forceinline__ int swz8(int i) { return i ^ (i >> 4); }
__host__ __device__ constexpr int cswz8(int i) { return i ^ (i >> 4); }

template<int P3, int P2, int P1, int P0>
struct BitMap {
    __device__ static int scatterDyn(int v) {
        return (((v >> 3) & 1) << P3) | (((v >> 2) & 1) << P2) |
               (((v >> 1) & 1) << P1) | ((v & 1) << P0);
    }
    static constexpr int scatter(int v) {
        return (((v >> 3) & 1) << P3) | (((v >> 2) & 1) << P2) |
               (((v >> 1) & 1) << P1) | ((v & 1) << P0);
    }
};

using WA = BitMap<7, 6, 5, 4>;  using LA = BitMap<3, 2, 1, 0>;   // q0,q1,q2,q3
using WB = BitMap<3, 2, 1, 0>;  using LB = BitMap<7, 6, 5, 4>;   // q4,q5,q6,q7
using WC = BitMap<7, 4, 3, 0>;  using LC = BitMap<6, 5, 2, 1>;   // q0,q3,q4,q7
using WD = BitMap<7, 5, 3, 1>;  using LD = BitMap<6, 4, 2, 0>;   // q0,q2,q4,q6

// dual re-layout: two independent streams, one wait point
template<class WO, class LO, class WN, class LN>
__device__ __forceinline__ void transition2(c32* slA, c32* slB, int c,
                                            c32 sA[16], c32 sB[16]) {
    const int uo = swz8(LO::scatterDyn(c));
#pragma unroll
    for (int r = 0; r < 16; ++r) slA[uo ^ cswz8(WO::scatter(r))] = sA[r];
#pragma unroll
    for (int r = 0; r < 16; ++r) slB[uo ^ cswz8(WO::scatter(r))] = sB[r];
    const int un = swz8(LN::scatterDyn(c));
#pragma unroll
    for (int r = 0; r < 16; ++r) sA[r] = slA[un ^ cswz8(WN::scatter(r))];
#pragma unroll
    for (int r = 0; r < 16; ++r) sB[r] = slB[un ^ cswz8(WN::scatter(r))];
}

constexpr int freePos(int A, int B, int k) {
    int cnt = 0;
    for (int p = 0; p < 4; ++p)
        if (p != A && p != B) { if (cnt == k) return p; ++cnt; }
    return -1;
}

// apply 4x4 gate; w0 at reg-bit A, w1 at reg-bit B (row = 2*bitA + bitB)
template<int A, int B>
__device__ __forceinline__ void gate(const c32 m[16], c32 s[16]) {
    constexpr int C0 = freePos(A, B, 0);
    constexpr int C1 = freePos(A, B, 1);
#pragma unroll
    for (int q = 0; q < 4; ++q) {
        const int base = ((q & 1) << C0) | (((q >> 1) & 1) << C1);
        const int i00 = base, i01 = base | (1 << B), i10 = base | (1 << A),
                  i11 = base | (1 << A) | (1 << B);
        c32 a0 = s[i00], a1 = s[i01], a2 = s[i10], a3 = s[i11];
        c32 r0 = cmul(m[0],  a0); r0 = cmad(m[1],  a1, r0); r0 = cmad(m[2],  a2, r0); r0 = cmad(m[3],  a3, r0);
        c32 r1 = cmul(m[4],  a0); r1 = cmad(m[5],  a1, r1); r1 = cmad(m[6],  a2, r1); r1 = cmad(m[7],  a3, r1);
        c32 r2 = cmul(m[8],  a0); r2 = cmad(m[9],  a1, r2); r2 = cmad(m[10], a2, r2); r2 = cmad(m[11], a3, r2);
        c32 r3 = cmul(m[12], a0); r3 = cmad(m[13], a1, r3); r3 = cmad(m[14], a2, r3); r3 = cmad(m[15], a3, r3);
        s[i00] = r0; s[i01] = r1; s[i10] = r2; s[i11] = r3;
    }
}

// dual gate: two independent dependency streams for the scheduler
template<int A, int B>
__device__ __forceinline__ void gate2(const c32 m[16], c32 sA[16], c32 sB[16]) {
    gate<A, B>(m, sA);
    gate<A, B>(m, sB);
}

__device__ __forceinline__ void loadm(const c32* gml, int idx, c32 m[16]) {
#pragma unroll
    for (int k = 0; k < 16; ++k) m[k] = gml[idx * 16 + k];   // LDS broadcast
}

// epilogue for one state (window D: qubit2 = reg-bit 2, qubit6 = reg-bit 0)
__device__ __forceinline__ void epilogue(const c32 s[16], int c, int b,
                                         float* __restrict__ out) {
    float e0 = 0, e1 = 0, e2 = 0, e3 = 0, e4 = 0, e5 = 0, e6 = 0, e7 = 0, e8 = 0;
#pragma unroll
    for (int q = 0; q < 4; ++q) {
        const int f = ((q & 1) << 1) | ((q & 2) << 2);
        c32 a00 = s[f], a01 = s[f | 1], a10 = s[f | 4], a11 = s[f | 5];
        float n00 = a00[0] * a00[0] + a00[1] * a00[1];
        float n01 = a01[0] * a01[0] + a01[1] * a01[1];
        float n10 = a10[0] * a10[0] + a10[1] * a10[1];
        float n11 = a11[0] * a11[0] + a11[1] * a11[1];
        float z2r = a00[0] * a10[0] + a00[1] * a10[1] + a01[0] * a11[0] + a01[1] * a11[1];
        float z2i = a00[0] * a10[1] - a00[1] * a10[0] + a01[0] * a11[1] - a01[1] * a11[0];
        float z6r = a00[0] * a01[0] + a00[1] * a01[1] + a10[0] * a11[0] + a10[1] * a11[1];
        float z6i = a00[0] * a01[1] - a00[1] * a01[0] + a10[0] * a11[1] - a10[1] * a11[0];
        float w1r = a00[0] * a11[0] + a00[1] * a11[1];
        float w2r = a01[0] * a10[0] + a01[1] * a10[1];
        e0 += 2.f * z2r;  e1 += 2.f * z2i;  e2 += n00 + n01 - n10 - n11;
        e3 += 2.f * z6r;  e4 += 2.f * z6i;  e5 += n00 - n01 + n10 - n11;
        e6 += 2.f * (w1r + w2r);  e7 += 2.f * (w2r - w1r);
        e8 += n00 - n01 - n10 + n11;
    }
    float e[9] = {e0, e1, e2, e3, e4, e5, e6, e7, e8};
#pragma unroll
    for (int mm = 0; mm < 9; ++mm) {
        float vv = e[mm];
#pragma unroll
        for (int o = 8; o; o >>= 1) vv += __shfl_xor(vv, o, 64);
        e[mm] = vv;
    }
    if (c == 0) {
#pragma unroll
        for (int mm = 0; mm < 9; ++mm) out[b * 9 + mm] = e[mm];
    }
}

__global__ __launch_bounds__(64, 1) void sim_kernel(const float* __restrict__ x,
                                                    const float* __restrict__ w,
                                                    float* __restrict__ out) {
    __shared__ c32 TR[8 * STRIDE];
    __shared__ c32 GML[80];
    const int lane = threadIdx.x;      // one wave per block
    const int st   = lane >> 4;        // slot within wave (0..3)
    const int c    = lane & 15;        // 16 lanes per state
    const int bA   = blockIdx.x * 8 + st;
    const int bB   = bA + 4;

    // issue both states' x loads first; matrix build overlaps the latency
    const float* xbA = x + (size_t)bA * 256 + c;
    const float* xbB = x + (size_t)bB * 256 + c;
    float vA[16], vB[16];
#pragma unroll
    for (int r = 0; r < 16; ++r) vA[r] = xbA[r << 4];
#pragma unroll
    for (int r = 0; r < 16; ++r) vB[r] = xbB[r << 4];

    if (lane < 20) build_col(w, lane, GML);

    float ssA = 0.f, ssB = 0.f;
#pragma unroll
    for (int r = 0; r < 16; ++r) { ssA = fmaf(vA[r], vA[r], ssA); ssB = fmaf(vB[r], vB[r], ssB); }
#pragma unroll
    for (int o = 8; o; o >>= 1) { ssA += __shfl_xor(ssA, o, 64); ssB += __shfl_xor(ssB, o, 64); }
    const float invA = 1.0f / sqrtf(ssA);
    const float invB = 1.0f / sqrtf(ssB);
    c32 sA[16], sB[16];
#pragma unroll
    for (int r = 0; r < 16; ++r) { sA[r] = mkc(vA[r] * invA, 0.f); sB[r] = mkc(vB[r] * invB, 0.f); }

    c32* slA = TR + st * STRIDE;
    c32* slB = TR + (st + 4) * STRIDE;
    c32 m[16];

    // ---- LAYER1 x2 (rolled) ----------------------------------------------
#pragma unroll 1
    for (int pass = 0; pass < 2; ++pass) {
        loadm(GML, pass, m);
        gate2<3, 2>(m, sA, sB); gate2<1, 0>(m, sA, sB); gate2<2, 1>(m, sA, sB); // (0,1)(2,3)(1,2)
        transition2<WA, LA, WB, LB>(slA, slB, c, sA, sB);
        gate2<3, 2>(m, sA, sB); gate2<1, 0>(m, sA, sB); gate2<2, 1>(m, sA, sB); // (4,5)(6,7)(5,6)
        transition2<WB, LB, WC, LC>(slA, slB, c, sA, sB);
        gate2<2, 1>(m, sA, sB); gate2<0, 3>(m, sA, sB);                         // (3,4)(7,0)
        if (pass == 0) transition2<WC, LC, WA, LA>(slA, slB, c, sA, sB);
        else           transition2<WC, LC, WD, LD>(slA, slB, c, sA, sB);
    }

    // ---- LAYER2 x2 in window D (no transitions) --------------------------
#pragma unroll 1
    for (int pp = 0; pp < 2; ++pp) {
        loadm(GML, 2 + pp, m);
        gate2<2, 1>(m, sA, sB); gate2<0, 3>(m, sA, sB);                         // (2,4)(6,0)
        gate2<3, 2>(m, sA, sB); gate2<1, 0>(m, sA, sB);                         // (0,2)(4,6)
    }
    // ---- LAYER3 ----------------------------------------------------------
    loadm(GML, 4, m);
    gate2<2, 0>(m, sA, sB);                                                     // (2,6)

    epilogue(sA, c, bA, out);
    epilogue(sB, c, bB, out);
}

extern "C" void kernel_launch(void* const* d_in, const int* in_sizes, int n_in,
                              void* d_out, int out_size, void* d_ws, size_t ws_size,
                              hipStream_t stream) {
    const float* x = (const float*)d_in[0];
    const float* w = (const float*)d_in[1];
    float* out = (float*)d_out;

    const int batch = in_sizes[0] / 256;   // 8192
    const int nblocks = batch / 8;         // 8 states per 64-thread block
    hipLaunchKernelGGL(sim_kernel, dim3(nblocks), dim3(64), 0, stream, x, w, out);
}